// Round 12
// baseline (352.119 us; speedup 1.0000x reference)
//
#include <hip/hip_runtime.h>
#include <hip/hip_fp16.h>

#define BKN 4        // nodes per hop wave (one 16-lane subgroup each)
#define RPN 64       // region slots per node (deg mean 16, sd 4 -> 16+12sigma)

typedef _Float16 half8 __attribute__((ext_vector_type(8)));
typedef _Float16 h4v __attribute__((ext_vector_type(4)));
typedef float floatx4 __attribute__((ext_vector_type(4)));

// ---------------- zero: deg[n] = 0 ----------------

__global__ void zero_kernel(int* __restrict__ p, int n) {
    int i = blockIdx.x * blockDim.x + threadIdx.x;
    if (i < n) p[i] = 0;
}

// ---------------- scatter: single-pass build ----------------
// Replaces init+passA+passB (two-level counting sort, 2 global roundtrips,
// 2 LDS sort networks): edge order within a target's run is irrelevant for
// summation, so scatter each edge directly into its target's fixed 64-slot
// region. deg counters (400KB) and region lines are L2-absorbed; atomics are
// device-scope (guide m20). deg[n] = true in-degree (excl self-loop).

__global__ __launch_bounds__(256) void scatter_kernel(const int* __restrict__ ei,
                                                      int* __restrict__ deg,
                                                      int* __restrict__ reg,
                                                      int E) {
    int i = blockIdx.x * blockDim.x + threadIdx.x;
    if (i < E) {
        int r = ei[i];
        int c = ei[E + i];
        int p = atomicAdd(&deg[c], 1);
        if (p < RPN) reg[(size_t)c * RPN + p] = r;   // overflow: P ~ 1e-24/node
    }
}

// ---------------- weight folding (25 blocks: parallel cold-fetch) ----------------
// Single-block fold is bound by one CU's outstanding-miss capacity (~1.4 GB/s
// on cold HBM). 25 blocks spread the cold fetch across 25 CUs (round-5: WIN).

__global__ __launch_bounds__(256) void fold_kernel(
    const float* __restrict__ W1, const float* __restrict__ b1,
    const float* __restrict__ W2, const float* __restrict__ b2,
    const float* __restrict__ W3, const float* __restrict__ b3,
    const float* __restrict__ W4,
    float* __restrict__ Wf1, float* __restrict__ Wf2,
    float* __restrict__ u, float* __restrict__ v) {
    __shared__ float As[64][64];
    __shared__ float gsl[64];
    int tid = threadIdx.x;
    int f = tid & 63;
    int w = __builtin_amdgcn_readfirstlane(tid >> 6);
    int blk = blockIdx.x;

    float w4c[64];
    #pragma unroll
    for (int k = 0; k < 64; ++k) w4c[k] = W4[k * 64 + f];

    if (blk < 24) {
        const int half = (blk < 16) ? 0 : 64;
        #pragma unroll 2
        for (int kk = 0; kk < 16; ++kk) {
            int k = w * 16 + kk;
            float a = 0.f;
            #pragma unroll
            for (int j = 0; j < 64; ++j)
                a += W3[(half + k) * 64 + j] * w4c[j];   // uniform -> s_load
            As[k][f] = a;
        }
        __syncthreads();
        const float* Wsrc = (blk < 16) ? W1 : W2;
        float* Wdst = (blk < 16) ? Wf1 : Wf2;
        int i = ((blk < 16) ? blk : (blk - 16)) * 4 + w;
        float a = 0.f;
        #pragma unroll
        for (int k = 0; k < 64; ++k)
            a += Wsrc[i * 64 + k] * As[k][f];
        Wdst[i * 64 + f] = a;
    } else {
        float g = 0.f;
        #pragma unroll
        for (int k = 0; k < 64; ++k) g += b1[k] * W3[k * 64 + f];
        #pragma unroll
        for (int k = 0; k < 64; ++k) g += b2[k] * W3[(64 + k) * 64 + f];
        if (w == 0) gsl[f] = g;
        __syncthreads();
        if (w == 0) {
            float uu = 0.f, vv = 0.f;
            #pragma unroll
            for (int k = 0; k < 64; ++k) {
                uu += gsl[k] * w4c[k];
                vv += b3[k] * w4c[k];
            }
            u[f] = uu;
            v[f] = vv;
        }
    }
}

// ---------------- linZ via MFMA: Z[n] = fp16( (X~[n] @ Wf) * dinv[n] ) ----------
// dinv computed on the fly from deg (no dinv array / pass).

__global__ __launch_bounds__(256) void linZ_kernel(
    const float* __restrict__ lat, const float* __restrict__ cond,
    const float* __restrict__ Wf1, const float* __restrict__ Wf2,
    const int* __restrict__ deg, _Float16* __restrict__ Z, int N) {
    __shared__ _Float16 Xs[64][104];   // pad 96->104: b128 frag reads 2-way only
    __shared__ _Float16 Wt[64][104];
    int tid = threadIdx.x;
    int n0 = blockIdx.x * 64;
    {
        const float4* lat4 = (const float4*)(lat + (size_t)n0 * 64);
        #pragma unroll
        for (int q = 0; q < 4; ++q) {
            int idx = q * 256 + tid;
            int row = idx >> 4;
            float4 v = make_float4(0.f, 0.f, 0.f, 0.f);
            if (n0 + row < N) v = lat4[idx];
            int col = (idx & 15) * 4;
            Xs[row][col + 0] = (_Float16)v.x;
            Xs[row][col + 1] = (_Float16)v.y;
            Xs[row][col + 2] = (_Float16)v.z;
            Xs[row][col + 3] = (_Float16)v.w;
        }
        const float4* cond4 = (const float4*)(cond + (size_t)n0 * 32);
        #pragma unroll
        for (int q = 0; q < 2; ++q) {
            int idx = q * 256 + tid;
            int row = idx >> 3;
            float4 v = make_float4(0.f, 0.f, 0.f, 0.f);
            if (n0 + row < N) v = cond4[idx];
            int col = 64 + (idx & 7) * 4;
            Xs[row][col + 0] = (_Float16)v.x;
            Xs[row][col + 1] = (_Float16)v.y;
            Xs[row][col + 2] = (_Float16)v.z;
            Xs[row][col + 3] = (_Float16)v.w;
        }
        for (int i = tid; i < 4096; i += 256) {
            int k = i >> 6, f = i & 63;
            Wt[f][k] = (_Float16)Wf1[i];
        }
        for (int i = tid; i < 2048; i += 256) {
            int k = i >> 6, f = i & 63;
            Wt[f][64 + k] = (_Float16)Wf2[i];
        }
    }
    __syncthreads();
    int lane = tid & 63, wave = tid >> 6;
    int quad = lane >> 4, l16 = lane & 15;
    floatx4 acc[4] = {};
    #pragma unroll
    for (int kc = 0; kc < 96; kc += 32) {
        half8 a = *(const half8*)&Xs[wave * 16 + l16][kc + quad * 8];
        #pragma unroll
        for (int nt = 0; nt < 4; ++nt) {
            half8 b = *(const half8*)&Wt[nt * 16 + l16][kc + quad * 8];
            acc[nt] = __builtin_amdgcn_mfma_f32_16x16x32_f16(a, b, acc[nt], 0, 0, 0);
        }
    }
    #pragma unroll
    for (int r = 0; r < 4; ++r) {
        int n = n0 + wave * 16 + quad * 4 + r;
        if (n < N) {
            float d = rsqrtf((float)deg[n] + 1.0f);
            #pragma unroll
            for (int nt = 0; nt < 4; ++nt)
                Z[(size_t)n * 64 + nt * 16 + l16] = (_Float16)(acc[nt][r] * d);
        }
    }
}

// ---------------- hop v6: fixed-stride regions, concurrent subgroup runs -------
// Subgroup g owns node b*4+g's run [n*RPN, n*RPN+min(deg,RPN)) concurrently;
// lane (g,fq) accumulates feats fq*4..+3 with plain adds (runs share one
// target -> no selects/butterflies). 8-deep unroll keeps 8 full-128B-row
// gathers in flight per subgroup (round-10 lesson: serial loops -> latency
// bound). dinv = rsqrt(deg+1) computed in-kernel (no array).
// Vp = fp16( dinv ⊙ true features ), row-major [N][64].
// FINAL=false: out16[n] = fp16( acc*d^2 + d*wvec[f] )
// FINAL=true : out32[n] = acc*d + wvec[f]
template <bool FINAL>
__global__ __launch_bounds__(256) void hop_kernel(
    const _Float16* __restrict__ Vp, const int* __restrict__ deg,
    const int* __restrict__ reg,
    const float* __restrict__ wvec, void* __restrict__ outv, int NB) {
    int lane = threadIdx.x & 63;
    int wave = threadIdx.x >> 6;
    int b = blockIdx.x * 4 + wave;
    if (b >= NB) return;
    int g  = lane >> 4;          // subgroup == node slot
    int fq = lane & 15;          // feature quad: feats fq*4 .. fq*4+3
    int n = b * BKN + g;

    float a0, a1, a2, a3;
    {
        h4v h = *(const h4v*)&Vp[(size_t)n * 64 + fq * 4];   // self-loop term
        a0 = (float)h[0]; a1 = (float)h[1]; a2 = (float)h[2]; a3 = (float)h[3];
    }
    int dn = deg[n];
    int cnt = min(dn, RPN);
    const int* run = reg + (size_t)n * RPN;
    int idx = 0;
    for (; idx + 8 <= cnt; idx += 8) {
        int r0 = run[idx + 0], r1 = run[idx + 1];
        int r2 = run[idx + 2], r3 = run[idx + 3];
        int r4 = run[idx + 4], r5 = run[idx + 5];
        int r6 = run[idx + 6], r7 = run[idx + 7];
        h4v h0 = *(const h4v*)&Vp[(size_t)r0 * 64 + fq * 4];
        h4v h1 = *(const h4v*)&Vp[(size_t)r1 * 64 + fq * 4];
        h4v h2 = *(const h4v*)&Vp[(size_t)r2 * 64 + fq * 4];
        h4v h3 = *(const h4v*)&Vp[(size_t)r3 * 64 + fq * 4];
        h4v h4_ = *(const h4v*)&Vp[(size_t)r4 * 64 + fq * 4];
        h4v h5 = *(const h4v*)&Vp[(size_t)r5 * 64 + fq * 4];
        h4v h6 = *(const h4v*)&Vp[(size_t)r6 * 64 + fq * 4];
        h4v h7 = *(const h4v*)&Vp[(size_t)r7 * 64 + fq * 4];
        a0 += ((float)h0[0] + (float)h1[0]) + ((float)h2[0] + (float)h3[0])
            + ((float)h4_[0] + (float)h5[0]) + ((float)h6[0] + (float)h7[0]);
        a1 += ((float)h0[1] + (float)h1[1]) + ((float)h2[1] + (float)h3[1])
            + ((float)h4_[1] + (float)h5[1]) + ((float)h6[1] + (float)h7[1]);
        a2 += ((float)h0[2] + (float)h1[2]) + ((float)h2[2] + (float)h3[2])
            + ((float)h4_[2] + (float)h5[2]) + ((float)h6[2] + (float)h7[2]);
        a3 += ((float)h0[3] + (float)h1[3]) + ((float)h2[3] + (float)h3[3])
            + ((float)h4_[3] + (float)h5[3]) + ((float)h6[3] + (float)h7[3]);
    }
    for (; idx + 4 <= cnt; idx += 4) {
        int r0 = run[idx + 0], r1 = run[idx + 1];
        int r2 = run[idx + 2], r3 = run[idx + 3];
        h4v h0 = *(const h4v*)&Vp[(size_t)r0 * 64 + fq * 4];
        h4v h1 = *(const h4v*)&Vp[(size_t)r1 * 64 + fq * 4];
        h4v h2 = *(const h4v*)&Vp[(size_t)r2 * 64 + fq * 4];
        h4v h3 = *(const h4v*)&Vp[(size_t)r3 * 64 + fq * 4];
        a0 += ((float)h0[0] + (float)h1[0]) + ((float)h2[0] + (float)h3[0]);
        a1 += ((float)h0[1] + (float)h1[1]) + ((float)h2[1] + (float)h3[1]);
        a2 += ((float)h0[2] + (float)h1[2]) + ((float)h2[2] + (float)h3[2]);
        a3 += ((float)h0[3] + (float)h1[3]) + ((float)h2[3] + (float)h3[3]);
    }
    for (; idx < cnt; ++idx) {
        int r = run[idx];
        h4v h = *(const h4v*)&Vp[(size_t)r * 64 + fq * 4];
        a0 += (float)h[0]; a1 += (float)h[1]; a2 += (float)h[2]; a3 += (float)h[3];
    }

    float d = rsqrtf((float)dn + 1.0f);
    float4 wv = *(const float4*)&wvec[fq * 4];
    if constexpr (FINAL) {
        float4 o;
        o.x = a0 * d + wv.x;
        o.y = a1 * d + wv.y;
        o.z = a2 * d + wv.z;
        o.w = a3 * d + wv.w;
        *(float4*)&((float*)outv)[(size_t)n * 64 + fq * 4] = o;
    } else {
        float dd = d * d;
        h4v o;
        o[0] = (_Float16)(a0 * dd + d * wv.x);
        o[1] = (_Float16)(a1 * dd + d * wv.y);
        o[2] = (_Float16)(a2 * dd + d * wv.z);
        o[3] = (_Float16)(a3 * dd + d * wv.w);
        *(h4v*)&((_Float16*)outv)[(size_t)n * 64 + fq * 4] = o;
    }
}

// ---------------- launch ----------------

static inline size_t align256(size_t x) { return (x + 255) & ~(size_t)255; }

extern "C" void kernel_launch(void* const* d_in, const int* in_sizes, int n_in,
                              void* d_out, int out_size, void* d_ws, size_t ws_size,
                              hipStream_t stream) {
    const float* latent = (const float*)d_in[0];
    const float* cond   = (const float*)d_in[1];
    const int*   ei     = (const int*)d_in[2];
    const float* W1 = (const float*)d_in[3];
    const float* b1 = (const float*)d_in[4];
    const float* W2 = (const float*)d_in[5];
    const float* b2 = (const float*)d_in[6];
    const float* W3 = (const float*)d_in[7];
    const float* b3 = (const float*)d_in[8];
    const float* W4 = (const float*)d_in[9];
    const float* b4 = (const float*)d_in[10];
    float* out = (float*)d_out;

    const int N = in_sizes[0] / 64;          // 100000
    const int E = in_sizes[2] / 2;           // 1600000
    const int NB = (N + BKN - 1) / BKN;      // 25000 4-node groups

    // workspace layout
    char* w = (char*)d_ws;
    size_t o = 0;
    int* deg = (int*)(w + o); o = align256(o + (size_t)N * 4);
    int* reg = (int*)(w + o); o = align256(o + (size_t)N * RPN * 4);  // 25.6MB
    float* Wf1 = (float*)(w + o); o = align256(o + 4096 * 4);
    float* Wf2 = (float*)(w + o); o = align256(o + 2048 * 4);
    float* uVec = (float*)(w + o); o = align256(o + 64 * 4);
    float* vVec = (float*)(w + o); o = align256(o + 64 * 4);
    _Float16* Z = (_Float16*)(w + o); o = align256(o + (size_t)N * 64 * 2);
    _Float16* P = (_Float16*)(w + o); o = align256(o + (size_t)N * 64 * 2);

    const int BS = 256;
    int gHop = (NB + 3) / 4;   // 6250 blocks, 4 waves each

    // ---- build: single-pass scatter into fixed per-node regions ----
    zero_kernel<<<(N + BS - 1) / BS, BS, 0, stream>>>(deg, N);
    scatter_kernel<<<(E + BS - 1) / BS, BS, 0, stream>>>(ei, deg, reg, E);

    // ---- weight fold (25 parallel blocks) + fused linear (MFMA) ----
    fold_kernel<<<25, BS, 0, stream>>>(W1, b1, W2, b2, W3, b3, W4, Wf1, Wf2, uVec, vVec);
    linZ_kernel<<<(N + 63) / 64, BS, 0, stream>>>(latent, cond, Wf1, Wf2, deg, Z, N);

    // ---- three hops (u, v folded into epilogues; b4 at final) ----
    hop_kernel<false><<<gHop, BS, 0, stream>>>(Z, deg, reg, uVec, (void*)P, NB);
    hop_kernel<false><<<gHop, BS, 0, stream>>>(P, deg, reg, vVec, (void*)Z, NB);
    hop_kernel<true ><<<gHop, BS, 0, stream>>>(Z, deg, reg, b4, (void*)out, NB);
}

// Round 13
// 315.645 us; speedup vs baseline: 1.1156x; 1.1156x over previous
//
#include <hip/hip_runtime.h>
#include <hip/hip_fp16.h>

#define BKN 4        // nodes per hop wave (one 16-lane subgroup each)
#define CBN 256      // nodes per coarse bin
#define CHUNK 4096   // edges per passA block
#define MAXBIN 5120  // fixed region per coarse bin (mean 4092, sd ~64 -> 16 sigma)

typedef _Float16 half8 __attribute__((ext_vector_type(8)));
typedef _Float16 h4v __attribute__((ext_vector_type(4)));
typedef float floatx4 __attribute__((ext_vector_type(4)));

// ---------------- init: curCB[i] = i*MAXBIN (fixed-region bases) ----------------

__global__ void init_cur_kernel(int* __restrict__ p, int n, int stride) {
    int i = blockIdx.x * blockDim.x + threadIdx.x;
    if (i < n) p[i] = i * stride;
}

// ---------------- passA: multisplit edges into fixed coarse-bin regions ----------
// packed: (r<<8) | (c & 255)
// NOTE round-12 lesson: direct per-edge scatter to final positions write-amplifies
// 15x (4B random writes dirty 64B lines -> 96MB writeback, 130us). The LDS-staged
// two-pass keeps all global writes coalesced; do not collapse it.

__global__ __launch_bounds__(256) void passA_kernel(const int* __restrict__ ei,
                                                    int* __restrict__ curCB,
                                                    unsigned* __restrict__ binned,
                                                    int E, int NCB) {
    __shared__ int lcnt[512];
    __shared__ int sA[512], sB[512];
    __shared__ int loffx[512];
    __shared__ int gbase[512];
    __shared__ int lpos[512];
    __shared__ unsigned stage[CHUNK];
    __shared__ unsigned short sbin[CHUNK];   // bin id per staged slot -> coalesced drain
    int tid = threadIdx.x;
    int base = blockIdx.x * CHUNK;
    for (int i = tid; i < 512; i += 256) lcnt[i] = 0;
    __syncthreads();
    unsigned pk[16]; int bin[16];
    #pragma unroll
    for (int q = 0; q < 16; ++q) {
        int e = base + q * 256 + tid;
        if (e < E) {
            int r = ei[e], c = ei[E + e];
            pk[q] = ((unsigned)r << 8) | (unsigned)(c & 255);
            bin[q] = c >> 8;
            atomicAdd(&lcnt[bin[q]], 1);
        } else bin[q] = -1;
    }
    __syncthreads();
    for (int i = tid; i < 512; i += 256) sA[i] = lcnt[i];
    __syncthreads();
    int* src = sA; int* dst = sB;
    for (int o = 1; o < 512; o <<= 1) {
        for (int i = tid; i < 512; i += 256)
            dst[i] = src[i] + (i >= o ? src[i - o] : 0);
        __syncthreads();
        int* t = src; src = dst; dst = t;
    }
    for (int i = tid; i < 512; i += 256) {
        int ex = (i > 0) ? src[i - 1] : 0;
        loffx[i] = ex;
        lpos[i] = ex;
        int c = lcnt[i];
        gbase[i] = (c > 0 && i < NCB) ? atomicAdd(&curCB[i], c) : 0;
    }
    __syncthreads();
    #pragma unroll
    for (int q = 0; q < 16; ++q) {
        if (bin[q] >= 0) {
            int p = atomicAdd(&lpos[bin[q]], 1);
            stage[p] = pk[q];
            sbin[p] = (unsigned short)bin[q];
        }
    }
    __syncthreads();
    int total = min(CHUNK, E - base);
    for (int idx = tid; idx < total; idx += 256) {
        int b2 = sbin[idx];
        binned[gbase[b2] + (idx - loffx[b2])] = stage[idx];
    }
}

// ---------------- passB: 256-bin fine sort by full target; emit bktR (r only),
// per-node runs offN/endN, and dinv. Edges within a run all share one target ->
// hop accumulates with plain adds (no selects). Verified correct rounds 9-11.

__global__ __launch_bounds__(256) void passB_kernel(const unsigned* __restrict__ binned,
                                                    const int* __restrict__ curCB,
                                                    int* __restrict__ bktR,
                                                    int* __restrict__ offN,
                                                    int* __restrict__ endN,
                                                    float* __restrict__ dinv,
                                                    int N, int NCB) {
    __shared__ unsigned raw[MAXBIN];
    __shared__ int stageR[MAXBIN];
    __shared__ int fcnt[256], foff[256], fpos[256];
    __shared__ int sA[256], sB[256];
    int i = blockIdx.x;
    int tid = threadIdx.x;
    int g0 = i * MAXBIN;
    int cnt = curCB[i] - g0;
    if (cnt > MAXBIN) cnt = MAXBIN;  // safety (16-sigma unreachable)
    fcnt[tid] = 0;
    __syncthreads();
    for (int idx = tid; idx < cnt; idx += 256) {
        unsigned pk = binned[g0 + idx];
        raw[idx] = pk;
        atomicAdd(&fcnt[pk & 255], 1);
    }
    __syncthreads();
    sA[tid] = fcnt[tid];
    __syncthreads();
    int* src = sA; int* dst = sB;
    for (int o = 1; o < 256; o <<= 1) {
        dst[tid] = src[tid] + (tid >= o ? src[tid - o] : 0);
        __syncthreads();
        int* t = src; src = dst; dst = t;
    }
    int excl = src[tid] - fcnt[tid];
    foff[tid] = excl;
    fpos[tid] = excl;
    __syncthreads();
    for (int idx = tid; idx < cnt; idx += 256) {
        unsigned pk = raw[idx];
        int p = atomicAdd(&fpos[pk & 255], 1);
        stageR[p] = (int)(pk >> 8);           // r only; target implicit by position
    }
    __syncthreads();
    for (int idx = tid; idx < cnt; idx += 256) bktR[g0 + idx] = stageR[idx];
    int n = i * CBN + tid;
    if (n < N) {
        offN[n] = g0 + foff[tid];
        endN[n] = g0 + foff[tid] + fcnt[tid];
        dinv[n] = rsqrtf((float)fcnt[tid] + 1.0f);
    }
}

// ---------------- weight folding (25 blocks: parallel cold-fetch) ----------------

__global__ __launch_bounds__(256) void fold_kernel(
    const float* __restrict__ W1, const float* __restrict__ b1,
    const float* __restrict__ W2, const float* __restrict__ b2,
    const float* __restrict__ W3, const float* __restrict__ b3,
    const float* __restrict__ W4,
    float* __restrict__ Wf1, float* __restrict__ Wf2,
    float* __restrict__ u, float* __restrict__ v) {
    __shared__ float As[64][64];
    __shared__ float gsl[64];
    int tid = threadIdx.x;
    int f = tid & 63;
    int w = __builtin_amdgcn_readfirstlane(tid >> 6);
    int blk = blockIdx.x;

    float w4c[64];
    #pragma unroll
    for (int k = 0; k < 64; ++k) w4c[k] = W4[k * 64 + f];

    if (blk < 24) {
        const int half = (blk < 16) ? 0 : 64;
        #pragma unroll 2
        for (int kk = 0; kk < 16; ++kk) {
            int k = w * 16 + kk;
            float a = 0.f;
            #pragma unroll
            for (int j = 0; j < 64; ++j)
                a += W3[(half + k) * 64 + j] * w4c[j];   // uniform -> s_load
            As[k][f] = a;
        }
        __syncthreads();
        const float* Wsrc = (blk < 16) ? W1 : W2;
        float* Wdst = (blk < 16) ? Wf1 : Wf2;
        int i = ((blk < 16) ? blk : (blk - 16)) * 4 + w;
        float a = 0.f;
        #pragma unroll
        for (int k = 0; k < 64; ++k)
            a += Wsrc[i * 64 + k] * As[k][f];
        Wdst[i * 64 + f] = a;
    } else {
        float g = 0.f;
        #pragma unroll
        for (int k = 0; k < 64; ++k) g += b1[k] * W3[k * 64 + f];
        #pragma unroll
        for (int k = 0; k < 64; ++k) g += b2[k] * W3[(64 + k) * 64 + f];
        if (w == 0) gsl[f] = g;
        __syncthreads();
        if (w == 0) {
            float uu = 0.f, vv = 0.f;
            #pragma unroll
            for (int k = 0; k < 64; ++k) {
                uu += gsl[k] * w4c[k];
                vv += b3[k] * w4c[k];
            }
            u[f] = uu;
            v[f] = vv;
        }
    }
}

// ---------------- linZ via MFMA: Z[n] = fp16( (X~[n] @ Wf) * dinv[n] ), row-major

__global__ __launch_bounds__(256) void linZ_kernel(
    const float* __restrict__ lat, const float* __restrict__ cond,
    const float* __restrict__ Wf1, const float* __restrict__ Wf2,
    const float* __restrict__ dinv, _Float16* __restrict__ Z, int N) {
    __shared__ _Float16 Xs[64][104];   // pad 96->104: b128 frag reads 2-way only
    __shared__ _Float16 Wt[64][104];
    int tid = threadIdx.x;
    int n0 = blockIdx.x * 64;
    {
        const float4* lat4 = (const float4*)(lat + (size_t)n0 * 64);
        #pragma unroll
        for (int q = 0; q < 4; ++q) {
            int idx = q * 256 + tid;
            int row = idx >> 4;
            float4 v = make_float4(0.f, 0.f, 0.f, 0.f);
            if (n0 + row < N) v = lat4[idx];
            int col = (idx & 15) * 4;
            Xs[row][col + 0] = (_Float16)v.x;
            Xs[row][col + 1] = (_Float16)v.y;
            Xs[row][col + 2] = (_Float16)v.z;
            Xs[row][col + 3] = (_Float16)v.w;
        }
        const float4* cond4 = (const float4*)(cond + (size_t)n0 * 32);
        #pragma unroll
        for (int q = 0; q < 2; ++q) {
            int idx = q * 256 + tid;
            int row = idx >> 3;
            float4 v = make_float4(0.f, 0.f, 0.f, 0.f);
            if (n0 + row < N) v = cond4[idx];
            int col = 64 + (idx & 7) * 4;
            Xs[row][col + 0] = (_Float16)v.x;
            Xs[row][col + 1] = (_Float16)v.y;
            Xs[row][col + 2] = (_Float16)v.z;
            Xs[row][col + 3] = (_Float16)v.w;
        }
        for (int i = tid; i < 4096; i += 256) {
            int k = i >> 6, f = i & 63;
            Wt[f][k] = (_Float16)Wf1[i];
        }
        for (int i = tid; i < 2048; i += 256) {
            int k = i >> 6, f = i & 63;
            Wt[f][64 + k] = (_Float16)Wf2[i];
        }
    }
    __syncthreads();
    int lane = tid & 63, wave = tid >> 6;
    int quad = lane >> 4, l16 = lane & 15;
    floatx4 acc[4] = {};
    #pragma unroll
    for (int kc = 0; kc < 96; kc += 32) {
        half8 a = *(const half8*)&Xs[wave * 16 + l16][kc + quad * 8];
        #pragma unroll
        for (int nt = 0; nt < 4; ++nt) {
            half8 b = *(const half8*)&Wt[nt * 16 + l16][kc + quad * 8];
            acc[nt] = __builtin_amdgcn_mfma_f32_16x16x32_f16(a, b, acc[nt], 0, 0, 0);
        }
    }
    #pragma unroll
    for (int r = 0; r < 4; ++r) {
        int n = n0 + wave * 16 + quad * 4 + r;
        if (n < N) {
            float d = dinv[n];
            #pragma unroll
            for (int nt = 0; nt < 4; ++nt)
                Z[(size_t)n * 64 + nt * 16 + l16] = (_Float16)(acc[nt][r] * d);
        }
    }
}

// ---------------- hop v5.1: concurrent subgroup runs, 16-deep gather pipeline --
// v5 (round 11): subgroup g owns node b*4+g's run concurrently; lane (g,fq)
// accumulates feats fq*4..+3 with plain adds. v5.1: first batch is 16-deep
// (mean run = 16, sd 4 -> one batch covers the typical node, halving serial
// latency chains); bktR loads are nontemporal (6.4MB streamed once, no reuse)
// and fp16 outputs are nontemporal stores -> L2 stays dedicated to Vp rows
// (the only reused data).
// Vp = fp16( dinv ⊙ true features ), row-major [N][64].
// FINAL=false: out16[n] = fp16( acc*d^2 + d*wvec[f] )  [NT store]
// FINAL=true : out32[n] = acc*d + wvec[f]
template <bool FINAL>
__global__ __launch_bounds__(256) void hop_kernel(
    const _Float16* __restrict__ Vp, const float* __restrict__ dinv,
    const int* __restrict__ offN, const int* __restrict__ endN,
    const int* __restrict__ bktR,
    const float* __restrict__ wvec, void* __restrict__ outv, int NB) {
    int lane = threadIdx.x & 63;
    int wave = threadIdx.x >> 6;
    int b = blockIdx.x * 4 + wave;
    if (b >= NB) return;
    int g  = lane >> 4;          // subgroup == node slot
    int fq = lane & 15;          // feature quad: feats fq*4 .. fq*4+3
    int n = b * BKN + g;

    float a0, a1, a2, a3;
    {
        h4v h = *(const h4v*)&Vp[(size_t)n * 64 + fq * 4];   // self-loop term
        a0 = (float)h[0]; a1 = (float)h[1]; a2 = (float)h[2]; a3 = (float)h[3];
    }
    int s = offN[n], e = endN[n];
    int idx = s;
    for (; idx + 16 <= e; idx += 16) {
        int r[16];
        #pragma unroll
        for (int j = 0; j < 16; ++j) r[j] = __builtin_nontemporal_load(&bktR[idx + j]);
        h4v h[16];
        #pragma unroll
        for (int j = 0; j < 16; ++j) h[j] = *(const h4v*)&Vp[(size_t)r[j] * 64 + fq * 4];
        #pragma unroll
        for (int j = 0; j < 16; ++j) {
            a0 += (float)h[j][0];
            a1 += (float)h[j][1];
            a2 += (float)h[j][2];
            a3 += (float)h[j][3];
        }
    }
    for (; idx + 4 <= e; idx += 4) {
        int r0 = __builtin_nontemporal_load(&bktR[idx + 0]);
        int r1 = __builtin_nontemporal_load(&bktR[idx + 1]);
        int r2 = __builtin_nontemporal_load(&bktR[idx + 2]);
        int r3 = __builtin_nontemporal_load(&bktR[idx + 3]);
        h4v h0 = *(const h4v*)&Vp[(size_t)r0 * 64 + fq * 4];
        h4v h1 = *(const h4v*)&Vp[(size_t)r1 * 64 + fq * 4];
        h4v h2 = *(const h4v*)&Vp[(size_t)r2 * 64 + fq * 4];
        h4v h3 = *(const h4v*)&Vp[(size_t)r3 * 64 + fq * 4];
        a0 += ((float)h0[0] + (float)h1[0]) + ((float)h2[0] + (float)h3[0]);
        a1 += ((float)h0[1] + (float)h1[1]) + ((float)h2[1] + (float)h3[1]);
        a2 += ((float)h0[2] + (float)h1[2]) + ((float)h2[2] + (float)h3[2]);
        a3 += ((float)h0[3] + (float)h1[3]) + ((float)h2[3] + (float)h3[3]);
    }
    for (; idx < e; ++idx) {
        int r = __builtin_nontemporal_load(&bktR[idx]);
        h4v h = *(const h4v*)&Vp[(size_t)r * 64 + fq * 4];
        a0 += (float)h[0]; a1 += (float)h[1]; a2 += (float)h[2]; a3 += (float)h[3];
    }

    float d = dinv[n];
    float4 wv = *(const float4*)&wvec[fq * 4];
    if constexpr (FINAL) {
        float4 o;
        o.x = a0 * d + wv.x;
        o.y = a1 * d + wv.y;
        o.z = a2 * d + wv.z;
        o.w = a3 * d + wv.w;
        *(float4*)&((float*)outv)[(size_t)n * 64 + fq * 4] = o;
    } else {
        float dd = d * d;
        h4v o;
        o[0] = (_Float16)(a0 * dd + d * wv.x);
        o[1] = (_Float16)(a1 * dd + d * wv.y);
        o[2] = (_Float16)(a2 * dd + d * wv.z);
        o[3] = (_Float16)(a3 * dd + d * wv.w);
        unsigned long long bits = __builtin_bit_cast(unsigned long long, o);
        __builtin_nontemporal_store(
            bits, (unsigned long long*)&((_Float16*)outv)[(size_t)n * 64 + fq * 4]);
    }
}

// ---------------- launch ----------------

static inline size_t align256(size_t x) { return (x + 255) & ~(size_t)255; }

extern "C" void kernel_launch(void* const* d_in, const int* in_sizes, int n_in,
                              void* d_out, int out_size, void* d_ws, size_t ws_size,
                              hipStream_t stream) {
    const float* latent = (const float*)d_in[0];
    const float* cond   = (const float*)d_in[1];
    const int*   ei     = (const int*)d_in[2];
    const float* W1 = (const float*)d_in[3];
    const float* b1 = (const float*)d_in[4];
    const float* W2 = (const float*)d_in[5];
    const float* b2 = (const float*)d_in[6];
    const float* W3 = (const float*)d_in[7];
    const float* b3 = (const float*)d_in[8];
    const float* W4 = (const float*)d_in[9];
    const float* b4 = (const float*)d_in[10];
    float* out = (float*)d_out;

    const int N = in_sizes[0] / 64;          // 100000
    const int E = in_sizes[2] / 2;           // 1600000
    const int NB  = (N + BKN - 1) / BKN;     // 25000 4-node groups
    const int NCB = (N + CBN - 1) / CBN;     // 391 coarse bins
    const int NCH = (E + CHUNK - 1) / CHUNK; // 391 chunks
    const size_t REG = (size_t)NCB * MAXBIN; // strided region total

    // workspace layout
    char* w = (char*)d_ws;
    size_t o = 0;
    int* curCB = (int*)(w + o); o = align256(o + (size_t)NCB * 4);
    int* offN  = (int*)(w + o); o = align256(o + (size_t)N * 4);
    int* endN  = (int*)(w + o); o = align256(o + (size_t)N * 4);
    float* dinv = (float*)(w + o); o = align256(o + (size_t)N * 4);
    float* Wf1 = (float*)(w + o); o = align256(o + 4096 * 4);
    float* Wf2 = (float*)(w + o); o = align256(o + 2048 * 4);
    float* uVec = (float*)(w + o); o = align256(o + 64 * 4);
    float* vVec = (float*)(w + o); o = align256(o + 64 * 4);
    unsigned* binned = (unsigned*)(w + o); o = align256(o + REG * 4);
    int* bktR        = (int*)(w + o); o = align256(o + REG * 4);
    _Float16* Z = (_Float16*)(w + o); o = align256(o + (size_t)N * 64 * 2);
    _Float16* P = (_Float16*)(w + o); o = align256(o + (size_t)N * 64 * 2);

    const int BS = 256;
    int gHop = (NB + 3) / 4;   // 6250 blocks, 4 waves each

    // ---- build: fixed-region counting sort; emits bktR, offN/endN, dinv ----
    init_cur_kernel<<<2, BS, 0, stream>>>(curCB, NCB, MAXBIN);
    passA_kernel<<<NCH, BS, 0, stream>>>(ei, curCB, binned, E, NCB);
    passB_kernel<<<NCB, BS, 0, stream>>>(binned, curCB, bktR, offN, endN, dinv, N, NCB);

    // ---- weight fold (25 parallel blocks) + fused linear (MFMA) ----
    fold_kernel<<<25, BS, 0, stream>>>(W1, b1, W2, b2, W3, b3, W4, Wf1, Wf2, uVec, vVec);
    linZ_kernel<<<(N + 63) / 64, BS, 0, stream>>>(latent, cond, Wf1, Wf2, dinv, Z, N);

    // ---- three hops (u, v folded into epilogues; b4 at final) ----
    hop_kernel<false><<<gHop, BS, 0, stream>>>(Z, dinv, offN, endN, bktR, uVec, (void*)P, NB);
    hop_kernel<false><<<gHop, BS, 0, stream>>>(P, dinv, offN, endN, bktR, vVec, (void*)Z, NB);
    hop_kernel<true ><<<gHop, BS, 0, stream>>>(Z, dinv, offN, endN, bktR, b4, (void*)out, NB);
}

// Round 14
// 265.879 us; speedup vs baseline: 1.3244x; 1.1872x over previous
//
#include <hip/hip_runtime.h>
#include <hip/hip_fp16.h>

#define BKN 4        // nodes per hop wave (one 16-lane subgroup each)
#define CBN 256      // nodes per coarse bin
#define CHUNK 4096   // edges per passA block
#define MAXBIN 5120  // fixed region per coarse bin (mean 4092, sd ~64 -> 16 sigma)

typedef _Float16 half8 __attribute__((ext_vector_type(8)));
typedef _Float16 h4v __attribute__((ext_vector_type(4)));
typedef float floatx4 __attribute__((ext_vector_type(4)));

// ---------------- init: curCB[i] = i*MAXBIN (fixed-region bases) ----------------

__global__ void init_cur_kernel(int* __restrict__ p, int n, int stride) {
    int i = blockIdx.x * blockDim.x + threadIdx.x;
    if (i < n) p[i] = i * stride;
}

// ---------------- passA: multisplit edges into fixed coarse-bin regions ----------
// packed: (r<<8) | (c & 255)
// Round-12 lesson: direct per-edge scatter to final positions write-amplifies 15x
// (4B random writes dirty 64B lines). The LDS-staged two-pass keeps global writes
// coalesced; do not collapse it.

__global__ __launch_bounds__(256) void passA_kernel(const int* __restrict__ ei,
                                                    int* __restrict__ curCB,
                                                    unsigned* __restrict__ binned,
                                                    int E, int NCB) {
    __shared__ int lcnt[512];
    __shared__ int sA[512], sB[512];
    __shared__ int loffx[512];
    __shared__ int gbase[512];
    __shared__ int lpos[512];
    __shared__ unsigned stage[CHUNK];
    __shared__ unsigned short sbin[CHUNK];   // bin id per staged slot -> coalesced drain
    int tid = threadIdx.x;
    int base = blockIdx.x * CHUNK;
    for (int i = tid; i < 512; i += 256) lcnt[i] = 0;
    __syncthreads();
    unsigned pk[16]; int bin[16];
    #pragma unroll
    for (int q = 0; q < 16; ++q) {
        int e = base + q * 256 + tid;
        if (e < E) {
            int r = ei[e], c = ei[E + e];
            pk[q] = ((unsigned)r << 8) | (unsigned)(c & 255);
            bin[q] = c >> 8;
            atomicAdd(&lcnt[bin[q]], 1);
        } else bin[q] = -1;
    }
    __syncthreads();
    for (int i = tid; i < 512; i += 256) sA[i] = lcnt[i];
    __syncthreads();
    int* src = sA; int* dst = sB;
    for (int o = 1; o < 512; o <<= 1) {
        for (int i = tid; i < 512; i += 256)
            dst[i] = src[i] + (i >= o ? src[i - o] : 0);
        __syncthreads();
        int* t = src; src = dst; dst = t;
    }
    for (int i = tid; i < 512; i += 256) {
        int ex = (i > 0) ? src[i - 1] : 0;
        loffx[i] = ex;
        lpos[i] = ex;
        int c = lcnt[i];
        gbase[i] = (c > 0 && i < NCB) ? atomicAdd(&curCB[i], c) : 0;
    }
    __syncthreads();
    #pragma unroll
    for (int q = 0; q < 16; ++q) {
        if (bin[q] >= 0) {
            int p = atomicAdd(&lpos[bin[q]], 1);
            stage[p] = pk[q];
            sbin[p] = (unsigned short)bin[q];
        }
    }
    __syncthreads();
    int total = min(CHUNK, E - base);
    for (int idx = tid; idx < total; idx += 256) {
        int b2 = sbin[idx];
        binned[gbase[b2] + (idx - loffx[b2])] = stage[idx];
    }
}

// ---------------- passB: 256-bin fine sort by full target; emit bktR (r only),
// per-node runs offN/endN, and dinv. v2: write bktR DIRECTLY from the position
// computation (positions fall inside this bin's 20KB L2-resident region, which
// is fully rewritten -> no write-amp; unlike round-12's 25MB random scatter).
// Drops the stageR LDS round-trip + 1 barrier; LDS 45->25KB (6 blocks/CU).

__global__ __launch_bounds__(256) void passB_kernel(const unsigned* __restrict__ binned,
                                                    const int* __restrict__ curCB,
                                                    int* __restrict__ bktR,
                                                    int* __restrict__ offN,
                                                    int* __restrict__ endN,
                                                    float* __restrict__ dinv,
                                                    int N, int NCB) {
    __shared__ unsigned raw[MAXBIN];
    __shared__ int fcnt[256], foff[256], fpos[256];
    __shared__ int sA[256], sB[256];
    int i = blockIdx.x;
    int tid = threadIdx.x;
    int g0 = i * MAXBIN;
    int cnt = curCB[i] - g0;
    if (cnt > MAXBIN) cnt = MAXBIN;  // safety (16-sigma unreachable)
    fcnt[tid] = 0;
    __syncthreads();
    for (int idx = tid; idx < cnt; idx += 256) {
        unsigned pk = binned[g0 + idx];
        raw[idx] = pk;
        atomicAdd(&fcnt[pk & 255], 1);
    }
    __syncthreads();
    sA[tid] = fcnt[tid];
    __syncthreads();
    int* src = sA; int* dst = sB;
    for (int o = 1; o < 256; o <<= 1) {
        dst[tid] = src[tid] + (tid >= o ? src[tid - o] : 0);
        __syncthreads();
        int* t = src; src = dst; dst = t;
    }
    int excl = src[tid] - fcnt[tid];
    foff[tid] = excl;
    fpos[tid] = excl;
    __syncthreads();
    for (int idx = tid; idx < cnt; idx += 256) {
        unsigned pk = raw[idx];
        int p = atomicAdd(&fpos[pk & 255], 1);
        bktR[g0 + p] = (int)(pk >> 8);        // direct; target implicit by position
    }
    int n = i * CBN + tid;
    if (n < N) {
        offN[n] = g0 + foff[tid];
        endN[n] = g0 + foff[tid] + fcnt[tid];
        dinv[n] = rsqrtf((float)fcnt[tid] + 1.0f);
    }
}

// ---------------- weight folding (25 blocks: parallel cold-fetch) ----------------

__global__ __launch_bounds__(256) void fold_kernel(
    const float* __restrict__ W1, const float* __restrict__ b1,
    const float* __restrict__ W2, const float* __restrict__ b2,
    const float* __restrict__ W3, const float* __restrict__ b3,
    const float* __restrict__ W4,
    float* __restrict__ Wf1, float* __restrict__ Wf2,
    float* __restrict__ u, float* __restrict__ v) {
    __shared__ float As[64][64];
    __shared__ float gsl[64];
    int tid = threadIdx.x;
    int f = tid & 63;
    int w = __builtin_amdgcn_readfirstlane(tid >> 6);
    int blk = blockIdx.x;

    float w4c[64];
    #pragma unroll
    for (int k = 0; k < 64; ++k) w4c[k] = W4[k * 64 + f];

    if (blk < 24) {
        const int half = (blk < 16) ? 0 : 64;
        #pragma unroll 2
        for (int kk = 0; kk < 16; ++kk) {
            int k = w * 16 + kk;
            float a = 0.f;
            #pragma unroll
            for (int j = 0; j < 64; ++j)
                a += W3[(half + k) * 64 + j] * w4c[j];   // uniform -> s_load
            As[k][f] = a;
        }
        __syncthreads();
        const float* Wsrc = (blk < 16) ? W1 : W2;
        float* Wdst = (blk < 16) ? Wf1 : Wf2;
        int i = ((blk < 16) ? blk : (blk - 16)) * 4 + w;
        float a = 0.f;
        #pragma unroll
        for (int k = 0; k < 64; ++k)
            a += Wsrc[i * 64 + k] * As[k][f];
        Wdst[i * 64 + f] = a;
    } else {
        float g = 0.f;
        #pragma unroll
        for (int k = 0; k < 64; ++k) g += b1[k] * W3[k * 64 + f];
        #pragma unroll
        for (int k = 0; k < 64; ++k) g += b2[k] * W3[(64 + k) * 64 + f];
        if (w == 0) gsl[f] = g;
        __syncthreads();
        if (w == 0) {
            float uu = 0.f, vv = 0.f;
            #pragma unroll
            for (int k = 0; k < 64; ++k) {
                uu += gsl[k] * w4c[k];
                vv += b3[k] * w4c[k];
            }
            u[f] = uu;
            v[f] = vv;
        }
    }
}

// ---------------- linZ via MFMA: Z[n] = fp16( (X~[n] @ Wf) * dinv[n] ), row-major

__global__ __launch_bounds__(256) void linZ_kernel(
    const float* __restrict__ lat, const float* __restrict__ cond,
    const float* __restrict__ Wf1, const float* __restrict__ Wf2,
    const float* __restrict__ dinv, _Float16* __restrict__ Z, int N) {
    __shared__ _Float16 Xs[64][104];   // pad 96->104: b128 frag reads 2-way only
    __shared__ _Float16 Wt[64][104];
    int tid = threadIdx.x;
    int n0 = blockIdx.x * 64;
    {
        const float4* lat4 = (const float4*)(lat + (size_t)n0 * 64);
        #pragma unroll
        for (int q = 0; q < 4; ++q) {
            int idx = q * 256 + tid;
            int row = idx >> 4;
            float4 v = make_float4(0.f, 0.f, 0.f, 0.f);
            if (n0 + row < N) v = lat4[idx];
            int col = (idx & 15) * 4;
            Xs[row][col + 0] = (_Float16)v.x;
            Xs[row][col + 1] = (_Float16)v.y;
            Xs[row][col + 2] = (_Float16)v.z;
            Xs[row][col + 3] = (_Float16)v.w;
        }
        const float4* cond4 = (const float4*)(cond + (size_t)n0 * 32);
        #pragma unroll
        for (int q = 0; q < 2; ++q) {
            int idx = q * 256 + tid;
            int row = idx >> 3;
            float4 v = make_float4(0.f, 0.f, 0.f, 0.f);
            if (n0 + row < N) v = cond4[idx];
            int col = 64 + (idx & 7) * 4;
            Xs[row][col + 0] = (_Float16)v.x;
            Xs[row][col + 1] = (_Float16)v.y;
            Xs[row][col + 2] = (_Float16)v.z;
            Xs[row][col + 3] = (_Float16)v.w;
        }
        for (int i = tid; i < 4096; i += 256) {
            int k = i >> 6, f = i & 63;
            Wt[f][k] = (_Float16)Wf1[i];
        }
        for (int i = tid; i < 2048; i += 256) {
            int k = i >> 6, f = i & 63;
            Wt[f][64 + k] = (_Float16)Wf2[i];
        }
    }
    __syncthreads();
    int lane = tid & 63, wave = tid >> 6;
    int quad = lane >> 4, l16 = lane & 15;
    floatx4 acc[4] = {};
    #pragma unroll
    for (int kc = 0; kc < 96; kc += 32) {
        half8 a = *(const half8*)&Xs[wave * 16 + l16][kc + quad * 8];
        #pragma unroll
        for (int nt = 0; nt < 4; ++nt) {
            half8 b = *(const half8*)&Wt[nt * 16 + l16][kc + quad * 8];
            acc[nt] = __builtin_amdgcn_mfma_f32_16x16x32_f16(a, b, acc[nt], 0, 0, 0);
        }
    }
    #pragma unroll
    for (int r = 0; r < 4; ++r) {
        int n = n0 + wave * 16 + quad * 4 + r;
        if (n < N) {
            float d = dinv[n];
            #pragma unroll
            for (int nt = 0; nt < 4; ++nt)
                Z[(size_t)n * 64 + nt * 16 + l16] = (_Float16)(acc[nt][r] * d);
        }
    }
}

// ---------------- hop v5 (round-11 verified): concurrent subgroup runs, 8-deep --
// Subgroup g owns node b*4+g's run concurrently; lane (g,fq) accumulates feats
// fq*4..+3 with plain adds (runs share one target -> no selects/butterflies).
// 8-deep unroll keeps 8 full-128B-row gathers in flight per subgroup.
// Round-13 lessons: NO nontemporal hints (bktR lines are sequentially consumed
// -> NT defeats L2 reuse, FETCH +8MB); NO 16-wide register batches (one long
// vmcnt wait instead of overlapping chains -> occupancy 42%).
// Vp = fp16( dinv ⊙ true features ), row-major [N][64].
// FINAL=false: out16[n] = fp16( acc*d^2 + d*wvec[f] )
// FINAL=true : out32[n] = acc*d + wvec[f]
template <bool FINAL>
__global__ __launch_bounds__(256) void hop_kernel(
    const _Float16* __restrict__ Vp, const float* __restrict__ dinv,
    const int* __restrict__ offN, const int* __restrict__ endN,
    const int* __restrict__ bktR,
    const float* __restrict__ wvec, void* __restrict__ outv, int NB) {
    int lane = threadIdx.x & 63;
    int wave = threadIdx.x >> 6;
    int b = blockIdx.x * 4 + wave;
    if (b >= NB) return;
    int g  = lane >> 4;          // subgroup == node slot
    int fq = lane & 15;          // feature quad: feats fq*4 .. fq*4+3
    int n = b * BKN + g;

    float a0, a1, a2, a3;
    {
        h4v h = *(const h4v*)&Vp[(size_t)n * 64 + fq * 4];   // self-loop term
        a0 = (float)h[0]; a1 = (float)h[1]; a2 = (float)h[2]; a3 = (float)h[3];
    }
    int s = offN[n], e = endN[n];
    int idx = s;
    for (; idx + 8 <= e; idx += 8) {
        int r0 = bktR[idx + 0], r1 = bktR[idx + 1];
        int r2 = bktR[idx + 2], r3 = bktR[idx + 3];
        int r4 = bktR[idx + 4], r5 = bktR[idx + 5];
        int r6 = bktR[idx + 6], r7 = bktR[idx + 7];
        h4v h0 = *(const h4v*)&Vp[(size_t)r0 * 64 + fq * 4];
        h4v h1 = *(const h4v*)&Vp[(size_t)r1 * 64 + fq * 4];
        h4v h2 = *(const h4v*)&Vp[(size_t)r2 * 64 + fq * 4];
        h4v h3 = *(const h4v*)&Vp[(size_t)r3 * 64 + fq * 4];
        h4v h4_ = *(const h4v*)&Vp[(size_t)r4 * 64 + fq * 4];
        h4v h5 = *(const h4v*)&Vp[(size_t)r5 * 64 + fq * 4];
        h4v h6 = *(const h4v*)&Vp[(size_t)r6 * 64 + fq * 4];
        h4v h7 = *(const h4v*)&Vp[(size_t)r7 * 64 + fq * 4];
        a0 += ((float)h0[0] + (float)h1[0]) + ((float)h2[0] + (float)h3[0])
            + ((float)h4_[0] + (float)h5[0]) + ((float)h6[0] + (float)h7[0]);
        a1 += ((float)h0[1] + (float)h1[1]) + ((float)h2[1] + (float)h3[1])
            + ((float)h4_[1] + (float)h5[1]) + ((float)h6[1] + (float)h7[1]);
        a2 += ((float)h0[2] + (float)h1[2]) + ((float)h2[2] + (float)h3[2])
            + ((float)h4_[2] + (float)h5[2]) + ((float)h6[2] + (float)h7[2]);
        a3 += ((float)h0[3] + (float)h1[3]) + ((float)h2[3] + (float)h3[3])
            + ((float)h4_[3] + (float)h5[3]) + ((float)h6[3] + (float)h7[3]);
    }
    for (; idx + 4 <= e; idx += 4) {
        int r0 = bktR[idx + 0], r1 = bktR[idx + 1];
        int r2 = bktR[idx + 2], r3 = bktR[idx + 3];
        h4v h0 = *(const h4v*)&Vp[(size_t)r0 * 64 + fq * 4];
        h4v h1 = *(const h4v*)&Vp[(size_t)r1 * 64 + fq * 4];
        h4v h2 = *(const h4v*)&Vp[(size_t)r2 * 64 + fq * 4];
        h4v h3 = *(const h4v*)&Vp[(size_t)r3 * 64 + fq * 4];
        a0 += ((float)h0[0] + (float)h1[0]) + ((float)h2[0] + (float)h3[0]);
        a1 += ((float)h0[1] + (float)h1[1]) + ((float)h2[1] + (float)h3[1]);
        a2 += ((float)h0[2] + (float)h1[2]) + ((float)h2[2] + (float)h3[2]);
        a3 += ((float)h0[3] + (float)h1[3]) + ((float)h2[3] + (float)h3[3]);
    }
    for (; idx < e; ++idx) {
        int r = bktR[idx];
        h4v h = *(const h4v*)&Vp[(size_t)r * 64 + fq * 4];
        a0 += (float)h[0]; a1 += (float)h[1]; a2 += (float)h[2]; a3 += (float)h[3];
    }

    float d = dinv[n];
    float4 wv = *(const float4*)&wvec[fq * 4];
    if constexpr (FINAL) {
        float4 o;
        o.x = a0 * d + wv.x;
        o.y = a1 * d + wv.y;
        o.z = a2 * d + wv.z;
        o.w = a3 * d + wv.w;
        *(float4*)&((float*)outv)[(size_t)n * 64 + fq * 4] = o;
    } else {
        float dd = d * d;
        h4v o;
        o[0] = (_Float16)(a0 * dd + d * wv.x);
        o[1] = (_Float16)(a1 * dd + d * wv.y);
        o[2] = (_Float16)(a2 * dd + d * wv.z);
        o[3] = (_Float16)(a3 * dd + d * wv.w);
        *(h4v*)&((_Float16*)outv)[(size_t)n * 64 + fq * 4] = o;
    }
}

// ---------------- launch ----------------

static inline size_t align256(size_t x) { return (x + 255) & ~(size_t)255; }

extern "C" void kernel_launch(void* const* d_in, const int* in_sizes, int n_in,
                              void* d_out, int out_size, void* d_ws, size_t ws_size,
                              hipStream_t stream) {
    const float* latent = (const float*)d_in[0];
    const float* cond   = (const float*)d_in[1];
    const int*   ei     = (const int*)d_in[2];
    const float* W1 = (const float*)d_in[3];
    const float* b1 = (const float*)d_in[4];
    const float* W2 = (const float*)d_in[5];
    const float* b2 = (const float*)d_in[6];
    const float* W3 = (const float*)d_in[7];
    const float* b3 = (const float*)d_in[8];
    const float* W4 = (const float*)d_in[9];
    const float* b4 = (const float*)d_in[10];
    float* out = (float*)d_out;

    const int N = in_sizes[0] / 64;          // 100000
    const int E = in_sizes[2] / 2;           // 1600000
    const int NB  = (N + BKN - 1) / BKN;     // 25000 4-node groups
    const int NCB = (N + CBN - 1) / CBN;     // 391 coarse bins
    const int NCH = (E + CHUNK - 1) / CHUNK; // 391 chunks
    const size_t REG = (size_t)NCB * MAXBIN; // strided region total

    // workspace layout
    char* w = (char*)d_ws;
    size_t o = 0;
    int* curCB = (int*)(w + o); o = align256(o + (size_t)NCB * 4);
    int* offN  = (int*)(w + o); o = align256(o + (size_t)N * 4);
    int* endN  = (int*)(w + o); o = align256(o + (size_t)N * 4);
    float* dinv = (float*)(w + o); o = align256(o + (size_t)N * 4);
    float* Wf1 = (float*)(w + o); o = align256(o + 4096 * 4);
    float* Wf2 = (float*)(w + o); o = align256(o + 2048 * 4);
    float* uVec = (float*)(w + o); o = align256(o + 64 * 4);
    float* vVec = (float*)(w + o); o = align256(o + 64 * 4);
    unsigned* binned = (unsigned*)(w + o); o = align256(o + REG * 4);
    int* bktR        = (int*)(w + o); o = align256(o + REG * 4);
    _Float16* Z = (_Float16*)(w + o); o = align256(o + (size_t)N * 64 * 2);
    _Float16* P = (_Float16*)(w + o); o = align256(o + (size_t)N * 64 * 2);

    const int BS = 256;
    int gHop = (NB + 3) / 4;   // 6250 blocks, 4 waves each

    // ---- build: fixed-region counting sort; emits bktR, offN/endN, dinv ----
    init_cur_kernel<<<2, BS, 0, stream>>>(curCB, NCB, MAXBIN);
    passA_kernel<<<NCH, BS, 0, stream>>>(ei, curCB, binned, E, NCB);
    passB_kernel<<<NCB, BS, 0, stream>>>(binned, curCB, bktR, offN, endN, dinv, N, NCB);

    // ---- weight fold (25 parallel blocks) + fused linear (MFMA) ----
    fold_kernel<<<25, BS, 0, stream>>>(W1, b1, W2, b2, W3, b3, W4, Wf1, Wf2, uVec, vVec);
    linZ_kernel<<<(N + 63) / 64, BS, 0, stream>>>(latent, cond, Wf1, Wf2, dinv, Z, N);

    // ---- three hops (u, v folded into epilogues; b4 at final) ----
    hop_kernel<false><<<gHop, BS, 0, stream>>>(Z, dinv, offN, endN, bktR, uVec, (void*)P, NB);
    hop_kernel<false><<<gHop, BS, 0, stream>>>(P, dinv, offN, endN, bktR, vVec, (void*)Z, NB);
    hop_kernel<true ><<<gHop, BS, 0, stream>>>(Z, dinv, offN, endN, bktR, b4, (void*)out, NB);
}

// Round 15
// 257.885 us; speedup vs baseline: 1.3654x; 1.0310x over previous
//
#include <hip/hip_runtime.h>
#include <hip/hip_fp16.h>

#define BKN 8        // nodes per hop wave (one 8-lane subgroup each)
#define CBN 256      // nodes per coarse bin
#define CHUNK 4096   // edges per passA block
#define MAXBIN 5120  // fixed region per coarse bin (mean 4092, sd ~64 -> 16 sigma)

typedef _Float16 half8 __attribute__((ext_vector_type(8)));
typedef _Float16 h4v __attribute__((ext_vector_type(4)));
typedef float floatx4 __attribute__((ext_vector_type(4)));

// ---------------- init: curCB[i] = i*MAXBIN (fixed-region bases) ----------------

__global__ void init_cur_kernel(int* __restrict__ p, int n, int stride) {
    int i = blockIdx.x * blockDim.x + threadIdx.x;
    if (i < n) p[i] = i * stride;
}

// ---------------- passA: multisplit edges into fixed coarse-bin regions ----------
// packed: (r<<8) | (c & 255)
// Round-12 lesson: direct per-edge scatter to final positions write-amplifies 15x
// (4B random writes dirty 64B lines). The LDS-staged two-pass keeps global writes
// coalesced; do not collapse it.

__global__ __launch_bounds__(256) void passA_kernel(const int* __restrict__ ei,
                                                    int* __restrict__ curCB,
                                                    unsigned* __restrict__ binned,
                                                    int E, int NCB) {
    __shared__ int lcnt[512];
    __shared__ int sA[512], sB[512];
    __shared__ int loffx[512];
    __shared__ int gbase[512];
    __shared__ int lpos[512];
    __shared__ unsigned stage[CHUNK];
    __shared__ unsigned short sbin[CHUNK];   // bin id per staged slot -> coalesced drain
    int tid = threadIdx.x;
    int base = blockIdx.x * CHUNK;
    for (int i = tid; i < 512; i += 256) lcnt[i] = 0;
    __syncthreads();
    unsigned pk[16]; int bin[16];
    #pragma unroll
    for (int q = 0; q < 16; ++q) {
        int e = base + q * 256 + tid;
        if (e < E) {
            int r = ei[e], c = ei[E + e];
            pk[q] = ((unsigned)r << 8) | (unsigned)(c & 255);
            bin[q] = c >> 8;
            atomicAdd(&lcnt[bin[q]], 1);
        } else bin[q] = -1;
    }
    __syncthreads();
    for (int i = tid; i < 512; i += 256) sA[i] = lcnt[i];
    __syncthreads();
    int* src = sA; int* dst = sB;
    for (int o = 1; o < 512; o <<= 1) {
        for (int i = tid; i < 512; i += 256)
            dst[i] = src[i] + (i >= o ? src[i - o] : 0);
        __syncthreads();
        int* t = src; src = dst; dst = t;
    }
    for (int i = tid; i < 512; i += 256) {
        int ex = (i > 0) ? src[i - 1] : 0;
        loffx[i] = ex;
        lpos[i] = ex;
        int c = lcnt[i];
        gbase[i] = (c > 0 && i < NCB) ? atomicAdd(&curCB[i], c) : 0;
    }
    __syncthreads();
    #pragma unroll
    for (int q = 0; q < 16; ++q) {
        if (bin[q] >= 0) {
            int p = atomicAdd(&lpos[bin[q]], 1);
            stage[p] = pk[q];
            sbin[p] = (unsigned short)bin[q];
        }
    }
    __syncthreads();
    int total = min(CHUNK, E - base);
    for (int idx = tid; idx < total; idx += 256) {
        int b2 = sbin[idx];
        binned[gbase[b2] + (idx - loffx[b2])] = stage[idx];
    }
}

// ---------------- passB: 256-bin fine sort by full target; emit bktR (r only),
// per-node runs offN/endN, and dinv. Round-14 lesson: direct global writes from
// the position computation regressed (+5us) -> keep the stageR LDS staging so
// the bktR write is a coalesced linear drain (verified round-11 form).

__global__ __launch_bounds__(256) void passB_kernel(const unsigned* __restrict__ binned,
                                                    const int* __restrict__ curCB,
                                                    int* __restrict__ bktR,
                                                    int* __restrict__ offN,
                                                    int* __restrict__ endN,
                                                    float* __restrict__ dinv,
                                                    int N, int NCB) {
    __shared__ unsigned raw[MAXBIN];
    __shared__ int stageR[MAXBIN];
    __shared__ int fcnt[256], foff[256], fpos[256];
    __shared__ int sA[256], sB[256];
    int i = blockIdx.x;
    int tid = threadIdx.x;
    int g0 = i * MAXBIN;
    int cnt = curCB[i] - g0;
    if (cnt > MAXBIN) cnt = MAXBIN;  // safety (16-sigma unreachable)
    fcnt[tid] = 0;
    __syncthreads();
    for (int idx = tid; idx < cnt; idx += 256) {
        unsigned pk = binned[g0 + idx];
        raw[idx] = pk;
        atomicAdd(&fcnt[pk & 255], 1);
    }
    __syncthreads();
    sA[tid] = fcnt[tid];
    __syncthreads();
    int* src = sA; int* dst = sB;
    for (int o = 1; o < 256; o <<= 1) {
        dst[tid] = src[tid] + (tid >= o ? src[tid - o] : 0);
        __syncthreads();
        int* t = src; src = dst; dst = t;
    }
    int excl = src[tid] - fcnt[tid];
    foff[tid] = excl;
    fpos[tid] = excl;
    __syncthreads();
    for (int idx = tid; idx < cnt; idx += 256) {
        unsigned pk = raw[idx];
        int p = atomicAdd(&fpos[pk & 255], 1);
        stageR[p] = (int)(pk >> 8);           // r only; target implicit by position
    }
    __syncthreads();
    for (int idx = tid; idx < cnt; idx += 256) bktR[g0 + idx] = stageR[idx];
    int n = i * CBN + tid;
    if (n < N) {
        offN[n] = g0 + foff[tid];
        endN[n] = g0 + foff[tid] + fcnt[tid];
        dinv[n] = rsqrtf((float)fcnt[tid] + 1.0f);
    }
}

// ---------------- weight folding (25 blocks: parallel cold-fetch) ----------------

__global__ __launch_bounds__(256) void fold_kernel(
    const float* __restrict__ W1, const float* __restrict__ b1,
    const float* __restrict__ W2, const float* __restrict__ b2,
    const float* __restrict__ W3, const float* __restrict__ b3,
    const float* __restrict__ W4,
    float* __restrict__ Wf1, float* __restrict__ Wf2,
    float* __restrict__ u, float* __restrict__ v) {
    __shared__ float As[64][64];
    __shared__ float gsl[64];
    int tid = threadIdx.x;
    int f = tid & 63;
    int w = __builtin_amdgcn_readfirstlane(tid >> 6);
    int blk = blockIdx.x;

    float w4c[64];
    #pragma unroll
    for (int k = 0; k < 64; ++k) w4c[k] = W4[k * 64 + f];

    if (blk < 24) {
        const int half = (blk < 16) ? 0 : 64;
        #pragma unroll 2
        for (int kk = 0; kk < 16; ++kk) {
            int k = w * 16 + kk;
            float a = 0.f;
            #pragma unroll
            for (int j = 0; j < 64; ++j)
                a += W3[(half + k) * 64 + j] * w4c[j];   // uniform -> s_load
            As[k][f] = a;
        }
        __syncthreads();
        const float* Wsrc = (blk < 16) ? W1 : W2;
        float* Wdst = (blk < 16) ? Wf1 : Wf2;
        int i = ((blk < 16) ? blk : (blk - 16)) * 4 + w;
        float a = 0.f;
        #pragma unroll
        for (int k = 0; k < 64; ++k)
            a += Wsrc[i * 64 + k] * As[k][f];
        Wdst[i * 64 + f] = a;
    } else {
        float g = 0.f;
        #pragma unroll
        for (int k = 0; k < 64; ++k) g += b1[k] * W3[k * 64 + f];
        #pragma unroll
        for (int k = 0; k < 64; ++k) g += b2[k] * W3[(64 + k) * 64 + f];
        if (w == 0) gsl[f] = g;
        __syncthreads();
        if (w == 0) {
            float uu = 0.f, vv = 0.f;
            #pragma unroll
            for (int k = 0; k < 64; ++k) {
                uu += gsl[k] * w4c[k];
                vv += b3[k] * w4c[k];
            }
            u[f] = uu;
            v[f] = vv;
        }
    }
}

// ---------------- linZ via MFMA: Z[n] = fp16( (X~[n] @ Wf) * dinv[n] ), row-major

__global__ __launch_bounds__(256) void linZ_kernel(
    const float* __restrict__ lat, const float* __restrict__ cond,
    const float* __restrict__ Wf1, const float* __restrict__ Wf2,
    const float* __restrict__ dinv, _Float16* __restrict__ Z, int N) {
    __shared__ _Float16 Xs[64][104];   // pad 96->104: b128 frag reads 2-way only
    __shared__ _Float16 Wt[64][104];
    int tid = threadIdx.x;
    int n0 = blockIdx.x * 64;
    {
        const float4* lat4 = (const float4*)(lat + (size_t)n0 * 64);
        #pragma unroll
        for (int q = 0; q < 4; ++q) {
            int idx = q * 256 + tid;
            int row = idx >> 4;
            float4 v = make_float4(0.f, 0.f, 0.f, 0.f);
            if (n0 + row < N) v = lat4[idx];
            int col = (idx & 15) * 4;
            Xs[row][col + 0] = (_Float16)v.x;
            Xs[row][col + 1] = (_Float16)v.y;
            Xs[row][col + 2] = (_Float16)v.z;
            Xs[row][col + 3] = (_Float16)v.w;
        }
        const float4* cond4 = (const float4*)(cond + (size_t)n0 * 32);
        #pragma unroll
        for (int q = 0; q < 2; ++q) {
            int idx = q * 256 + tid;
            int row = idx >> 3;
            float4 v = make_float4(0.f, 0.f, 0.f, 0.f);
            if (n0 + row < N) v = cond4[idx];
            int col = 64 + (idx & 7) * 4;
            Xs[row][col + 0] = (_Float16)v.x;
            Xs[row][col + 1] = (_Float16)v.y;
            Xs[row][col + 2] = (_Float16)v.z;
            Xs[row][col + 3] = (_Float16)v.w;
        }
        for (int i = tid; i < 4096; i += 256) {
            int k = i >> 6, f = i & 63;
            Wt[f][k] = (_Float16)Wf1[i];
        }
        for (int i = tid; i < 2048; i += 256) {
            int k = i >> 6, f = i & 63;
            Wt[f][64 + k] = (_Float16)Wf2[i];
        }
    }
    __syncthreads();
    int lane = tid & 63, wave = tid >> 6;
    int quad = lane >> 4, l16 = lane & 15;
    floatx4 acc[4] = {};
    #pragma unroll
    for (int kc = 0; kc < 96; kc += 32) {
        half8 a = *(const half8*)&Xs[wave * 16 + l16][kc + quad * 8];
        #pragma unroll
        for (int nt = 0; nt < 4; ++nt) {
            half8 b = *(const half8*)&Wt[nt * 16 + l16][kc + quad * 8];
            acc[nt] = __builtin_amdgcn_mfma_f32_16x16x32_f16(a, b, acc[nt], 0, 0, 0);
        }
    }
    #pragma unroll
    for (int r = 0; r < 4; ++r) {
        int n = n0 + wave * 16 + quad * 4 + r;
        if (n < N) {
            float d = dinv[n];
            #pragma unroll
            for (int nt = 0; nt < 4; ++nt)
                Z[(size_t)n * 64 + nt * 16 + l16] = (_Float16)(acc[nt][r] * d);
        }
    }
}

// ---------------- hop v6: 8 nodes/wave, 16B-lane row loads, 8-deep pipeline ----
// v5 (round 11, verified): concurrent per-subgroup runs, plain adds, 8-deep.
// v6: subgroups shrink 16->8 lanes; each lane loads 16B (8 feats) of its
// edge's row, so one wave-wide load instruction covers 8 edges' rows (vs 4)
// -> row-load + bktR instruction count per edge HALVED. VALU/edge unchanged
// (feature math is fixed). Depth-8 overlapping chains retained (round-13
// lesson: wider register batches serialize on one vmcnt; NT hints defeat the
// sequential bktR line reuse -- both reverted).
// Vp = fp16( dinv ⊙ true features ), row-major [N][64]. N % 8 == 0.
// FINAL=false: out16[n] = fp16( acc*d^2 + d*wvec[f] )
// FINAL=true : out32[n] = acc*d + wvec[f]
template <bool FINAL>
__global__ __launch_bounds__(256) void hop_kernel(
    const _Float16* __restrict__ Vp, const float* __restrict__ dinv,
    const int* __restrict__ offN, const int* __restrict__ endN,
    const int* __restrict__ bktR,
    const float* __restrict__ wvec, void* __restrict__ outv, int NB) {
    int lane = threadIdx.x & 63;
    int wave = threadIdx.x >> 6;
    int b = blockIdx.x * 4 + wave;
    if (b >= NB) return;
    int g  = lane >> 3;          // subgroup 0..7 == node slot
    int fl = lane & 7;           // feature octet: feats fl*8 .. fl*8+7
    int n = b * BKN + g;

    float a[8];
    {
        half8 h = *(const half8*)&Vp[(size_t)n * 64 + fl * 8];   // self-loop term
        #pragma unroll
        for (int j = 0; j < 8; ++j) a[j] = (float)h[j];
    }
    int s = offN[n], e = endN[n];
    int idx = s;
    for (; idx + 8 <= e; idx += 8) {
        int r0 = bktR[idx + 0], r1 = bktR[idx + 1];
        int r2 = bktR[idx + 2], r3 = bktR[idx + 3];
        int r4 = bktR[idx + 4], r5 = bktR[idx + 5];
        int r6 = bktR[idx + 6], r7 = bktR[idx + 7];
        half8 h0 = *(const half8*)&Vp[(size_t)r0 * 64 + fl * 8];
        half8 h1 = *(const half8*)&Vp[(size_t)r1 * 64 + fl * 8];
        half8 h2 = *(const half8*)&Vp[(size_t)r2 * 64 + fl * 8];
        half8 h3 = *(const half8*)&Vp[(size_t)r3 * 64 + fl * 8];
        half8 h4_ = *(const half8*)&Vp[(size_t)r4 * 64 + fl * 8];
        half8 h5 = *(const half8*)&Vp[(size_t)r5 * 64 + fl * 8];
        half8 h6 = *(const half8*)&Vp[(size_t)r6 * 64 + fl * 8];
        half8 h7 = *(const half8*)&Vp[(size_t)r7 * 64 + fl * 8];
        #pragma unroll
        for (int j = 0; j < 8; ++j) {
            a[j] += (((float)h0[j] + (float)h1[j]) + ((float)h2[j] + (float)h3[j]))
                  + (((float)h4_[j] + (float)h5[j]) + ((float)h6[j] + (float)h7[j]));
        }
    }
    for (; idx + 4 <= e; idx += 4) {
        int r0 = bktR[idx + 0], r1 = bktR[idx + 1];
        int r2 = bktR[idx + 2], r3 = bktR[idx + 3];
        half8 h0 = *(const half8*)&Vp[(size_t)r0 * 64 + fl * 8];
        half8 h1 = *(const half8*)&Vp[(size_t)r1 * 64 + fl * 8];
        half8 h2 = *(const half8*)&Vp[(size_t)r2 * 64 + fl * 8];
        half8 h3 = *(const half8*)&Vp[(size_t)r3 * 64 + fl * 8];
        #pragma unroll
        for (int j = 0; j < 8; ++j) {
            a[j] += ((float)h0[j] + (float)h1[j]) + ((float)h2[j] + (float)h3[j]);
        }
    }
    for (; idx < e; ++idx) {
        int r = bktR[idx];
        half8 h = *(const half8*)&Vp[(size_t)r * 64 + fl * 8];
        #pragma unroll
        for (int j = 0; j < 8; ++j) a[j] += (float)h[j];
    }

    float d = dinv[n];
    float4 wv0 = *(const float4*)&wvec[fl * 8 + 0];
    float4 wv1 = *(const float4*)&wvec[fl * 8 + 4];
    if constexpr (FINAL) {
        float4 o0, o1;
        o0.x = a[0] * d + wv0.x;
        o0.y = a[1] * d + wv0.y;
        o0.z = a[2] * d + wv0.z;
        o0.w = a[3] * d + wv0.w;
        o1.x = a[4] * d + wv1.x;
        o1.y = a[5] * d + wv1.y;
        o1.z = a[6] * d + wv1.z;
        o1.w = a[7] * d + wv1.w;
        *(float4*)&((float*)outv)[(size_t)n * 64 + fl * 8 + 0] = o0;
        *(float4*)&((float*)outv)[(size_t)n * 64 + fl * 8 + 4] = o1;
    } else {
        float dd = d * d;
        half8 o;
        o[0] = (_Float16)(a[0] * dd + d * wv0.x);
        o[1] = (_Float16)(a[1] * dd + d * wv0.y);
        o[2] = (_Float16)(a[2] * dd + d * wv0.z);
        o[3] = (_Float16)(a[3] * dd + d * wv0.w);
        o[4] = (_Float16)(a[4] * dd + d * wv1.x);
        o[5] = (_Float16)(a[5] * dd + d * wv1.y);
        o[6] = (_Float16)(a[6] * dd + d * wv1.z);
        o[7] = (_Float16)(a[7] * dd + d * wv1.w);
        *(half8*)&((_Float16*)outv)[(size_t)n * 64 + fl * 8] = o;
    }
}

// ---------------- launch ----------------

static inline size_t align256(size_t x) { return (x + 255) & ~(size_t)255; }

extern "C" void kernel_launch(void* const* d_in, const int* in_sizes, int n_in,
                              void* d_out, int out_size, void* d_ws, size_t ws_size,
                              hipStream_t stream) {
    const float* latent = (const float*)d_in[0];
    const float* cond   = (const float*)d_in[1];
    const int*   ei     = (const int*)d_in[2];
    const float* W1 = (const float*)d_in[3];
    const float* b1 = (const float*)d_in[4];
    const float* W2 = (const float*)d_in[5];
    const float* b2 = (const float*)d_in[6];
    const float* W3 = (const float*)d_in[7];
    const float* b3 = (const float*)d_in[8];
    const float* W4 = (const float*)d_in[9];
    const float* b4 = (const float*)d_in[10];
    float* out = (float*)d_out;

    const int N = in_sizes[0] / 64;          // 100000
    const int E = in_sizes[2] / 2;           // 1600000
    const int NB  = (N + BKN - 1) / BKN;     // 12500 8-node groups
    const int NCB = (N + CBN - 1) / CBN;     // 391 coarse bins
    const int NCH = (E + CHUNK - 1) / CHUNK; // 391 chunks
    const size_t REG = (size_t)NCB * MAXBIN; // strided region total

    // workspace layout
    char* w = (char*)d_ws;
    size_t o = 0;
    int* curCB = (int*)(w + o); o = align256(o + (size_t)NCB * 4);
    int* offN  = (int*)(w + o); o = align256(o + (size_t)N * 4);
    int* endN  = (int*)(w + o); o = align256(o + (size_t)N * 4);
    float* dinv = (float*)(w + o); o = align256(o + (size_t)N * 4);
    float* Wf1 = (float*)(w + o); o = align256(o + 4096 * 4);
    float* Wf2 = (float*)(w + o); o = align256(o + 2048 * 4);
    float* uVec = (float*)(w + o); o = align256(o + 64 * 4);
    float* vVec = (float*)(w + o); o = align256(o + 64 * 4);
    unsigned* binned = (unsigned*)(w + o); o = align256(o + REG * 4);
    int* bktR        = (int*)(w + o); o = align256(o + REG * 4);
    _Float16* Z = (_Float16*)(w + o); o = align256(o + (size_t)N * 64 * 2);
    _Float16* P = (_Float16*)(w + o); o = align256(o + (size_t)N * 64 * 2);

    const int BS = 256;
    int gHop = (NB + 3) / 4;   // 3125 blocks, 4 waves each

    // ---- build: fixed-region counting sort; emits bktR, offN/endN, dinv ----
    init_cur_kernel<<<2, BS, 0, stream>>>(curCB, NCB, MAXBIN);
    passA_kernel<<<NCH, BS, 0, stream>>>(ei, curCB, binned, E, NCB);
    passB_kernel<<<NCB, BS, 0, stream>>>(binned, curCB, bktR, offN, endN, dinv, N, NCB);

    // ---- weight fold (25 parallel blocks) + fused linear (MFMA) ----
    fold_kernel<<<25, BS, 0, stream>>>(W1, b1, W2, b2, W3, b3, W4, Wf1, Wf2, uVec, vVec);
    linZ_kernel<<<(N + 63) / 64, BS, 0, stream>>>(latent, cond, Wf1, Wf2, dinv, Z, N);

    // ---- three hops (u, v folded into epilogues; b4 at final) ----
    hop_kernel<false><<<gHop, BS, 0, stream>>>(Z, dinv, offN, endN, bktR, uVec, (void*)P, NB);
    hop_kernel<false><<<gHop, BS, 0, stream>>>(P, dinv, offN, endN, bktR, vVec, (void*)Z, NB);
    hop_kernel<true ><<<gHop, BS, 0, stream>>>(Z, dinv, offN, endN, bktR, b4, (void*)out, NB);
}